// Round 3
// baseline (212.301 us; speedup 1.0000x reference)
//
#include <hip/hip_runtime.h>
#include <stdint.h>
#include <math.h>

#define SEQ 4096
#define DM  1024
#define NH  16
#define DH  64
#define LOG2E 1.44269504088896341f

typedef short bf16x8 __attribute__((ext_vector_type(8)));
typedef short bf16x4 __attribute__((ext_vector_type(4)));
typedef float f32x4  __attribute__((ext_vector_type(4)));
typedef uint32_t u32x4 __attribute__((ext_vector_type(4)));

typedef const __attribute__((address_space(1))) short* gptr_t;
typedef __attribute__((address_space(3))) short* lptr_t;

__device__ __forceinline__ short f2bf(float f) {
    union { float f; uint32_t u; } x; x.f = f;
    uint32_t r = (x.u + 0x7fffu + ((x.u >> 16) & 1u)) >> 16;
    return (short)r;
}
// pack two f32 -> dword of two bf16 (RNE), lo in low half — 1 VALU op
__device__ __forceinline__ uint32_t cvtpk(float lo, float hi) {
    uint32_t r;
    asm("v_cvt_pk_bf16_f32 %0, %1, %2" : "=v"(r) : "v"(lo), "v"(hi));
    return r;
}

__device__ __forceinline__ void load_lds16(const short* g, const short* l) {
    __builtin_amdgcn_global_load_lds((gptr_t)(uintptr_t)g,
                                     (lptr_t)(uint32_t)(uintptr_t)l, 16, 0, 0);
}

// ---- fused prep: blocks [0,2048) convert x fp32->bf16; blocks [2048,2816)
//      transpose w [1024][3072] -> wtb [3072][1024] bf16, Q cols pre-scaled ----
__global__ __launch_bounds__(256) void cvt_fused(const float* __restrict__ x,
                                                 const float* __restrict__ w,
                                                 short* __restrict__ xb,
                                                 short* __restrict__ wtb) {
    __shared__ float T[64][69];
    const int b = blockIdx.x;
    if (b < 2048) {
        const int i = (b * 256 + threadIdx.x) * 8;
        float4 a0 = ((const float4*)(x + i))[0];
        float4 a1 = ((const float4*)(x + i))[1];
        bf16x8 p;
        p[0]=f2bf(a0.x); p[1]=f2bf(a0.y); p[2]=f2bf(a0.z); p[3]=f2bf(a0.w);
        p[4]=f2bf(a1.x); p[5]=f2bf(a1.y); p[6]=f2bf(a1.z); p[7]=f2bf(a1.w);
        *(bf16x8*)(xb + i) = p;
        return;
    }
    const int bb = b - 2048;
    const int n0 = (bb % 48) * 64, k0 = (bb / 48) * 64;
    const int t = threadIdx.x;
    {
        const int kr = t >> 4, nc = (t & 15) * 4;
        #pragma unroll
        for (int i = 0; i < 4; ++i) {
            float4 v = *(const float4*)(w + (size_t)(k0 + kr + i * 16) * 3072 + n0 + nc);
            T[kr + i * 16][nc + 0] = v.x; T[kr + i * 16][nc + 1] = v.y;
            T[kr + i * 16][nc + 2] = v.z; T[kr + i * 16][nc + 3] = v.w;
        }
    }
    __syncthreads();
    const int nr = t >> 4, kc = (t & 15) * 4;
    #pragma unroll
    for (int i = 0; i < 4; ++i) {
        const int n = n0 + nr + i * 16;
        const float sc = (n >= 1024 && n < 2048) ? (LOG2E / 32.0f) : 1.0f;
        short4 o;
        o.x = f2bf(T[kc + 0][nr + i * 16] * sc);
        o.y = f2bf(T[kc + 1][nr + i * 16] * sc);
        o.z = f2bf(T[kc + 2][nr + i * 16] * sc);
        o.w = f2bf(T[kc + 3][nr + i * 16] * sc);
        *(short4*)(wtb + (size_t)n * 1024 + k0 + kc) = o;
    }
}

// ---- QKV GEMM (m97 structure): 128x128 tile, BK=64, global_load_lds.
//      V^T stored with keys tau-permuted within each 64-tile:
//      tau(32a+16b+4c+r) = 32a+8c+4b+r  (field swap), so attn's PV
//      B-fragment is one contiguous b128 per (ks,ldiv). ----
__global__ __launch_bounds__(256) void qkv_gemm(const short* __restrict__ xb,
                                                const short* __restrict__ wtb,
                                                short* __restrict__ kq,
                                                short* __restrict__ vt) {
    __shared__ short As[128 * 64];
    __shared__ short Bs[128 * 64];
    const int col0 = blockIdx.y * 128, row0 = blockIdx.x * 128;
    const int tid = threadIdx.x, w = tid >> 6, lane = tid & 63;
    const int lmod = lane & 15, ldiv = lane >> 4;
    const int wr = (w >> 1) * 64, wc = (w & 1) * 64;

    f32x4 acc[4][4] = {};
    const short* Ag = xb  + (size_t)row0 * DM;
    const short* Bg = wtb + (size_t)col0 * DM;

    for (int k0 = 0; k0 < DM; k0 += 64) {
        __syncthreads();
        #pragma unroll
        for (int t = 0; t < 4; ++t) {
            const int o = (w * 4 + t) * 1024 + lane * 16;
            const int r = o >> 7, cs = (o & 127) >> 1;
            load_lds16(Ag + (size_t)r * DM + k0 + cs, As + (w * 4 + t) * 512);
            load_lds16(Bg + (size_t)r * DM + k0 + cs, Bs + (w * 4 + t) * 512);
        }
        __syncthreads();
        #pragma unroll
        for (int ks = 0; ks < 2; ++ks) {
            bf16x8 af[4], bf[4];
            #pragma unroll
            for (int i = 0; i < 4; ++i)
                af[i] = *(const bf16x8*)(As + (wr + i * 16 + lmod) * 64 + ks * 32 + ldiv * 8);
            #pragma unroll
            for (int j = 0; j < 4; ++j)
                bf[j] = *(const bf16x8*)(Bs + (wc + j * 16 + lmod) * 64 + ks * 32 + ldiv * 8);
            #pragma unroll
            for (int i = 0; i < 4; ++i)
                #pragma unroll
                for (int j = 0; j < 4; ++j)
                    acc[i][j] = __builtin_amdgcn_mfma_f32_16x16x32_bf16(af[i], bf[j], acc[i][j], 0, 0, 0);
        }
    }

    if (col0 < 2048) {
        #pragma unroll
        for (int i = 0; i < 4; ++i)
            #pragma unroll
            for (int j = 0; j < 4; ++j)
                #pragma unroll
                for (int r = 0; r < 4; ++r)
                    kq[(size_t)(row0 + wr + i * 16 + ldiv * 4 + r) * 2048
                       + col0 + wc + j * 16 + lmod] = f2bf(acc[i][j][r]);
    } else {
        #pragma unroll
        for (int i = 0; i < 4; ++i) {
            const int ig = row0 + wr + i * 16 + ldiv * 4;
            const int kk = ig & 63;
            // tau: 32a+16b+4c -> 32a+8c+4b
            const int kkp = (kk & 32) | ((kk & 12) << 1) | ((kk & 16) >> 2);
            const int igp = (ig & ~63) | kkp;
            #pragma unroll
            for (int j = 0; j < 4; ++j) {
                const int cg = col0 + wc + j * 16 + lmod - 2048;
                const int h = cg >> 6, d = cg & 63;
                bf16x4 p;
                p[0]=f2bf(acc[i][j][0]); p[1]=f2bf(acc[i][j][1]);
                p[2]=f2bf(acc[i][j][2]); p[3]=f2bf(acc[i][j][3]);
                *(bf16x4*)(vt + (size_t)(h * 64 + d) * SEQ + igp) = p;
            }
        }
    }
}

// ---- flash attention, split-K 2-way.
//  v4: in-register softmax (swapped QK^T, lane-local P), V pre-tau-permuted
//  in vt so the PV B-fragment is ONE b128 at the proven conflict-free
//  offsets (same form as K reads, 0 conflicts in v2). cvt_pk packing.
//  T3-minimal pipeline: double-buffered K/V, stage(kt+1) -> compute(kt) ->
//  one __syncthreads per tile (its vmcnt drain lands after compute).
//  LDS 32KB -> 4 blocks/CU. ----
__global__ __launch_bounds__(256, 4) void attn(const short* __restrict__ kq,
                                               const short* __restrict__ vt,
                                               float* __restrict__ o0,
                                               float* __restrict__ o1,
                                               float* __restrict__ ls0,
                                               float* __restrict__ ls1) {
    __shared__ short Ks[2][64 * 64];
    __shared__ short Vs[2][64 * 64];

    // band-interleaved decode: per-CU resident set sums to 66 units
    const int b = blockIdx.x;
    const int band = b >> 8, pos = b & 255, g = pos >> 5;
    const int qt = (band & 1) ? (24 - band * 8 + g) : (31 - band * 8 - g);
    const int h = (pos >> 1) & 15, s = pos & 1;

    const int tid = threadIdx.x, w = tid >> 6, lane = tid & 63;
    const int lmod = lane & 15, ldiv = lane >> 4;
    const float slope2 = exp2f(-0.5f * (float)(h + 1)) * LOG2E;

    // staging: wave w stages rows w*16..w*16+15 of both K and V tiles.
    // lane l -> row w*16 + (l>>3) (+8 for 2nd load), phys chunk l&7;
    // global logical chunk = phys ^ (row&7)  (swizzle on source address).
    const int sr0 = w * 16 + (lane >> 3), sr1 = sr0 + 8;
    const int sc0 = (lane & 7) ^ (sr0 & 7), sc1 = (lane & 7) ^ (sr1 & 7);

    const int xorm = lmod & 7;                 // read-side swizzle
    const int cxs0 = (ldiv ^ xorm) * 8;        // phys short offset, chunk ldiv
    const int cxs1 = ((4 + ldiv) ^ xorm) * 8;  // phys short offset, chunk 4+ldiv

    const int rowbase = qt * 128 + w * 32;

    // Q fragments (2 m-blocks x 2 d-chunks) — the MFMA B operand
    bf16x8 qf[2][2];
    #pragma unroll
    for (int m = 0; m < 2; ++m) {
        const short* qp = kq + (size_t)(rowbase + m * 16 + lmod) * 2048 + 1024 + h * 64;
        qf[m][0] = *(const bf16x8*)(qp + ldiv * 8);
        qf[m][1] = *(const bf16x8*)(qp + 32 + ldiv * 8);
    }
    // swapped layout: lane holds S[k = kt*64 + nt*16 + 4*ldiv + r][q = lmod]
    int db2[2];
    f32x4 pre4[2];
    #pragma unroll
    for (int m = 0; m < 2; ++m) {
        db2[m] = 4 * ldiv - (rowbase + m * 16 + lmod);
        #pragma unroll
        for (int r = 0; r < 4; ++r) pre4[m][r] = slope2 * (float)(db2[m] + r);
    }

    f32x4 O[2][4] = {};
    f32x4 ls4[2] = {};
    const int kt0 = s ? (qt + 1) : 0;
    const int kt1 = s ? (2 * qt + 2) : (qt + 1);

    auto stage = [&](int kt_, int p) {
        const short* kb = kq + (size_t)(kt_ * 64) * 2048 + h * 64;
        load_lds16(kb + (size_t)sr0 * 2048 + sc0 * 8, &Ks[p][(w * 16) * 64]);
        load_lds16(kb + (size_t)sr1 * 2048 + sc1 * 8, &Ks[p][(w * 16 + 8) * 64]);
        const short* vb = vt + (size_t)(h * 64) * SEQ + kt_ * 64;
        load_lds16(vb + (size_t)sr0 * SEQ + sc0 * 8, &Vs[p][(w * 16) * 64]);
        load_lds16(vb + (size_t)sr1 * SEQ + sc1 * 8, &Vs[p][(w * 16 + 8) * 64]);
    };

    stage(kt0, 0);
    __syncthreads();   // tile kt0 resident
    int par = 0;

    for (int kt = kt0; kt < kt1; ++kt) {
        const short* Kb = &Ks[par][0];
        const short* Vb = &Vs[par][0];
        if (kt + 1 < kt1) stage(kt + 1, par ^ 1);   // prefetch under compute

        const bool diag = (kt >= 2 * qt);
        const int dt = kt * 64;
        const float cb = slope2 * (float)dt;

        __builtin_amdgcn_s_setprio(1);
        #pragma unroll
        for (int ks = 0; ks < 2; ++ks) {       // 32-key chunk for PV
            u32x4 pk0, pk1;
            #pragma unroll
            for (int j1 = 0; j1 < 2; ++j1) {   // K 16-row block nt = 2ks+j1
                const int nt = ks * 2 + j1;
                const float cn = cb + slope2 * (float)(nt * 16);
                f32x4 s0 = pre4[0] + cn;
                f32x4 s1 = pre4[1] + cn;
                const short* krow = Kb + (nt * 16 + lmod) * 64;
                const bf16x8 kf0 = *(const bf16x8*)(krow + cxs0);
                const bf16x8 kf1 = *(const bf16x8*)(krow + cxs1);
                s0 = __builtin_amdgcn_mfma_f32_16x16x32_bf16(kf0, qf[0][0], s0, 0, 0, 0);
                s0 = __builtin_amdgcn_mfma_f32_16x16x32_bf16(kf1, qf[0][1], s0, 0, 0, 0);
                s1 = __builtin_amdgcn_mfma_f32_16x16x32_bf16(kf0, qf[1][0], s1, 0, 0, 0);
                s1 = __builtin_amdgcn_mfma_f32_16x16x32_bf16(kf1, qf[1][1], s1, 0, 0, 0);

                f32x4 p0, p1;
                if (diag) {
                    #pragma unroll
                    for (int r = 0; r < 4; ++r) {
                        float v0 = s0[r], v1 = s1[r];
                        if (dt + nt * 16 + r + db2[0] > 0) v0 = -1e30f;
                        if (dt + nt * 16 + r + db2[1] > 0) v1 = -1e30f;
                        p0[r] = __builtin_amdgcn_exp2f(v0);
                        p1[r] = __builtin_amdgcn_exp2f(v1);
                    }
                } else {
                    #pragma unroll
                    for (int r = 0; r < 4; ++r) {
                        p0[r] = __builtin_amdgcn_exp2f(s0[r]);
                        p1[r] = __builtin_amdgcn_exp2f(s1[r]);
                    }
                }
                ls4[0] += p0;
                ls4[1] += p1;
                pk0[j1 * 2]     = cvtpk(p0[0], p0[1]);
                pk0[j1 * 2 + 1] = cvtpk(p0[2], p0[3]);
                pk1[j1 * 2]     = cvtpk(p1[0], p1[1]);
                pk1[j1 * 2 + 1] = cvtpk(p1[2], p1[3]);
            }
            const bf16x8 pa0 = __builtin_bit_cast(bf16x8, pk0);
            const bf16x8 pa1 = __builtin_bit_cast(bf16x8, pk1);
            const int cxo = ks ? cxs1 : cxs0;
            #pragma unroll
            for (int nt2 = 0; nt2 < 4; ++nt2) {
                const bf16x8 vf = *(const bf16x8*)(Vb + (nt2 * 16 + lmod) * 64 + cxo);
                O[0][nt2] = __builtin_amdgcn_mfma_f32_16x16x32_bf16(pa0, vf, O[0][nt2], 0, 0, 0);
                O[1][nt2] = __builtin_amdgcn_mfma_f32_16x16x32_bf16(pa1, vf, O[1][nt2], 0, 0, 0);
            }
        }
        __builtin_amdgcn_s_setprio(0);

        __syncthreads();   // drains prefetch; frees buf[par] for restage
        par ^= 1;
    }

    // row sums: lane holds partial for q = lmod; reduce across ldiv groups
    float lsum[2];
    #pragma unroll
    for (int m = 0; m < 2; ++m) {
        float v = (ls4[m][0] + ls4[m][1]) + (ls4[m][2] + ls4[m][3]);
        v += __shfl_xor(v, 16);
        v += __shfl_xor(v, 32);
        lsum[m] = v;
    }

    float* ob = s ? o1 : o0;
    float* lb = s ? ls1 : ls0;
    #pragma unroll
    for (int m = 0; m < 2; ++m) {
        const int i0 = rowbase + m * 16 + ldiv * 4;
        #pragma unroll
        for (int nt2 = 0; nt2 < 4; ++nt2)
            #pragma unroll
            for (int r = 0; r < 4; ++r)
                ob[(size_t)(i0 + r) * DM + h * 64 + nt2 * 16 + lmod] = O[m][nt2][r];
    }
    if (ldiv == 0) {
        #pragma unroll
        for (int m = 0; m < 2; ++m)
            lb[h * SEQ + rowbase + m * 16 + lmod] = lsum[m];
    }
}

// ---- combine: out = (O0 + O1) / (l0 + l1) ----
__global__ __launch_bounds__(256) void combine(float* __restrict__ out,
                                               const float* __restrict__ opart,
                                               const float* __restrict__ ls0,
                                               const float* __restrict__ ls1) {
    const int i8 = (blockIdx.x * 256 + threadIdx.x) * 8;
    const int row = i8 >> 10, col = i8 & 1023, h = col >> 6;
    const float l = ls0[h * SEQ + row] + ls1[h * SEQ + row];
    const float rc = 1.0f / l;
    float4 a0 = *(const float4*)(out + i8);
    float4 a1 = *(const float4*)(out + i8 + 4);
    float4 b0 = *(const float4*)(opart + i8);
    float4 b1 = *(const float4*)(opart + i8 + 4);
    float4 c0, c1;
    c0.x = (a0.x + b0.x) * rc; c0.y = (a0.y + b0.y) * rc;
    c0.z = (a0.z + b0.z) * rc; c0.w = (a0.w + b0.w) * rc;
    c1.x = (a1.x + b1.x) * rc; c1.y = (a1.y + b1.y) * rc;
    c1.z = (a1.z + b1.z) * rc; c1.w = (a1.w + b1.w) * rc;
    *(float4*)(out + i8) = c0;
    *(float4*)(out + i8 + 4) = c1;
}

extern "C" void kernel_launch(void* const* d_in, const int* in_sizes, int n_in,
                              void* d_out, int out_size, void* d_ws, size_t ws_size,
                              hipStream_t stream) {
    const float* x = (const float*)d_in[0];   // [1,4096,1024] fp32
    const float* w = (const float*)d_in[1];   // [1024,3072] fp32
    float* out = (float*)d_out;

    char* ws = (char*)d_ws;
    short* kq    = (short*)(ws);                        // 16 MB: K|Q [4096][2048]
    short* vt    = (short*)(ws + ((size_t)16 << 20));   //  8 MB: V^T [16][64][4096] (tau-permuted keys)
    short* xb    = (short*)(ws + ((size_t)24 << 20));   //  8 MB: x bf16 (dead after gemm)
    short* wtb   = (short*)(ws + ((size_t)32 << 20));   //  6 MB: w^T bf16 (dead after gemm)
    float* opart = (float*)(ws + ((size_t)24 << 20));   // 16 MB: split-1 partial O (reuses xb/wtb)
    float* ls0   = (float*)(ws + ((size_t)40 << 20));   // 256 KB
    float* ls1   = (float*)(ws + ((size_t)40 << 20) + (256 << 10));

    cvt_fused<<<2048 + 768, 256, 0, stream>>>(x, w, xb, wtb);
    qkv_gemm <<<dim3(SEQ / 128, 3072 / 128), 256, 0, stream>>>(xb, wtb, kq, vt);
    attn     <<<1024, 256, 0, stream>>>(kq, vt, out, opart, ls0, ls1);
    combine  <<<SEQ * DM / (256 * 8), 256, 0, stream>>>(out, opart, ls0, ls1);
}